// Round 16
// baseline (175.858 us; speedup 1.0000x reference)
//
#include <hip/hip_runtime.h>
#include <cstdint>

#define Bn 128
#define Nn 4096
#define Dn 64
#define Kn 8
#define PBn 8
#define NCHUNKn (Nn / PBn)   // 512
#define NITn (NCHUNKn / 32)  // 16
#define LN_EPSf 1e-5f
#define EPSf 1e-8f
#define LOG2Ef 1.4426950408889634f

typedef unsigned short u16x8 __attribute__((ext_vector_type(8)));
typedef float f32x2 __attribute__((ext_vector_type(2)));

#if __has_builtin(__builtin_amdgcn_fdot2_f32_bf16)
#define USE_DOT2 1
typedef __bf16 bf16v2 __attribute__((ext_vector_type(2)));
static __device__ __forceinline__ bf16v2 asbf2(uint32_t u) {
    union { uint32_t u; bf16v2 v; } c; c.u = u; return c.v;
}
#else
#define USE_DOT2 0
#endif

#if __has_builtin(__builtin_elementwise_fma)
#define USE_PKFMA 1
#else
#define USE_PKFMA 0
#endif

static __device__ __forceinline__ uint16_t f2bf(float f) {
    union { float f; uint32_t u; } v; v.f = f;
    return (uint16_t)((v.u + 0x7fffu + ((v.u >> 16) & 1u)) >> 16);
}
static __device__ __forceinline__ float bflo(uint32_t u) {
    union { uint32_t u; float f; } v; v.u = u << 16; return v.f;
}
static __device__ __forceinline__ float bfhi(uint32_t u) {
    union { uint32_t u; float f; } v; v.u = u & 0xffff0000u; return v.f;
}

// DPP butterfly add (validated R3-R15): 0xB1 ^1, 0x4E ^2, 0x141 ^7, 0x128 ror8.
template <int CTRL>
static __device__ __forceinline__ float dppadd(float x) {
    int p = __builtin_amdgcn_update_dpp(0, __float_as_int(x), CTRL, 0xf, 0xf, false);
    return x + __int_as_float(p);
}

// ---------------- kM: M = (Wq^T @ Wk) / sqrt(D) * log2(e) ----------------
__global__ __launch_bounds__(256) void kM(const float* __restrict__ Wq,
                                          const float* __restrict__ Wk,
                                          float* __restrict__ M) {
    const int idx = blockIdx.x * 256 + threadIdx.x;  // 4096
    const int e = idx >> 6, f = idx & 63;
    float acc = 0.f;
#pragma unroll 8
    for (int d = 0; d < 64; ++d) acc += Wq[d * 64 + e] * Wk[d * 64 + f];
    M[idx] = acc * 0.125f * LOG2Ef;
}

// ------- kinit_qk: slots = mu+exp(ls)*noise; qk0 = LN(slots)@M (R8) ------
__global__ __launch_bounds__(256) void kinit_qk_full(
    const float* __restrict__ noise, const float* __restrict__ mu,
    const float* __restrict__ ls, const float* __restrict__ M,
    const float* __restrict__ lsg, const float* __restrict__ lsb,
    float* __restrict__ slots, float* __restrict__ qk) {
    __shared__ float sraw[Kn * Dn];
    __shared__ float sln[Kn][68];
    const int t = threadIdx.x;
    const int b = blockIdx.x;

    if (t < 128) {
        const int base = (b * 128 + t) * 4;
        const int d = base & 63;
        float4 nz = *(const float4*)(noise + base);
        float4 m4 = *(const float4*)(mu + d);
        float4 s4 = *(const float4*)(ls + d);
        float4 o;
        o.x = m4.x + __expf(s4.x) * nz.x;
        o.y = m4.y + __expf(s4.y) * nz.y;
        o.z = m4.z + __expf(s4.z) * nz.z;
        o.w = m4.w + __expf(s4.w) * nz.w;
        *(float4*)(slots + base) = o;
        *(float4*)(sraw + t * 4) = o;
    }
    __syncthreads();
    if (t < 128) {
        const int row = t >> 4, l16 = t & 15;
        float4 v4 = *(const float4*)(sraw + row * 64 + l16 * 4);
        float s1 = v4.x + v4.y + v4.z + v4.w;
        float s2 = v4.x * v4.x + v4.y * v4.y + v4.z * v4.z + v4.w * v4.w;
        s1 = dppadd<0xB1>(s1); s2 = dppadd<0xB1>(s2);
        s1 = dppadd<0x4E>(s1); s2 = dppadd<0x4E>(s2);
        s1 = dppadd<0x141>(s1); s2 = dppadd<0x141>(s2);
        s1 = dppadd<0x128>(s1); s2 = dppadd<0x128>(s2);
        const float mean = s1 * (1.0f / 64.0f);
        const float var = s2 * (1.0f / 64.0f) - mean * mean;
        const float rstd = rsqrtf(var + LN_EPSf);
        const float xs[4] = {v4.x, v4.y, v4.z, v4.w};
#pragma unroll
        for (int i = 0; i < 4; ++i) {
            const int dcol = l16 * 4 + i;
            sln[row][dcol] = (xs[i] - mean) * rstd * lsg[dcol] + lsb[dcol];
        }
    }
    __syncthreads();
    for (int o = t; o < 512; o += 256) {
        const int kk = o >> 6, j = o & 63;
        float a = 0.f;
#pragma unroll 8
        for (int e = 0; e < 64; ++e) a += sln[kk][e] * M[e * 64 + j];
        qk[b * 512 + o] = a;
    }
}

// ---------------- k2: attention pass over an N-chunk ---------------------
// MODE 0: read raw fp32 inputs, inline LN (dc-lane DPP), write xbf, attend.
//         (2-deep prefetch, unchanged R14.)
// MODE 1: read bf16 xbf.  ILP-2 (R16): each body processes TWO positions
//         (independent dot2/DPP/exp2 chains interleave -> hides dep-chain
//         latency); 2-pair ping-pong named-register prefetch.
template <int MODE>
__global__ __launch_bounds__(256) void k2_attn(
    const float* __restrict__ inp, const uint16_t* __restrict__ xbf_in,
    uint16_t* __restrict__ xbf_out, const float* __restrict__ qkg,
    const float* __restrict__ lng, const float* __restrict__ lnb,
    float* __restrict__ partials) {
    __shared__ float qld[Kn][64];
    __shared__ float red[16 * 552];
    __shared__ float redas[16][8];

    const int t = threadIdx.x;
    const int b = blockIdx.x >> 3;
    const int part = blockIdx.x & 7;

    if (t < 128) *(float4*)(&qld[0][0] + t * 4) = *(const float4*)(qkg + b * 512 + t * 4);
    __syncthreads();

    const int dc = t & 7;
    const int pg = t >> 3;  // 0..31

#if USE_DOT2
    uint32_t qrp[8][4];
#pragma unroll
    for (int kk = 0; kk < 8; ++kk)
#pragma unroll
        for (int p = 0; p < 4; ++p)
            qrp[kk][p] = (uint32_t)f2bf(qld[kk][dc * 8 + 2 * p]) |
                         ((uint32_t)f2bf(qld[kk][dc * 8 + 2 * p + 1]) << 16);
#else
    float qr[8][8];
#pragma unroll
    for (int kk = 0; kk < 8; ++kk) {
        float4 q0 = *(const float4*)&qld[kk][dc * 8];
        float4 q1 = *(const float4*)&qld[kk][dc * 8 + 4];
        qr[kk][0] = q0.x; qr[kk][1] = q0.y; qr[kk][2] = q0.z; qr[kk][3] = q0.w;
        qr[kk][4] = q1.x; qr[kk][5] = q1.y; qr[kk][6] = q1.z; qr[kk][7] = q1.w;
    }
#endif

    // LN gamma/beta for my 8 dims (MODE 0 only)
    float gv[8], bt[8];
    if (MODE == 0) {
#pragma unroll
        for (int i = 0; i < 8; ++i) { gv[i] = lng[dc * 8 + i]; bt[i] = lnb[dc * 8 + i]; }
    }

#if USE_PKFMA
    f32x2 upd2[8][4];
#pragma unroll
    for (int kk = 0; kk < 8; ++kk)
#pragma unroll
        for (int i = 0; i < 4; ++i) upd2[kk][i] = (f32x2){0.f, 0.f};
#else
    float upd[8][8];
#pragma unroll
    for (int kk = 0; kk < 8; ++kk)
#pragma unroll
        for (int i = 0; i < 8; ++i) upd[kk][i] = 0.f;
#endif
    float asum[8];
#pragma unroll
    for (int kk = 0; kk < 8; ++kk) asum[kk] = 0.f;

    const long chunkoff = ((long)b * Nn + part * NCHUNKn) * 64 + dc * 8;
    const uint16_t* xbase = xbf_in + chunkoff + (long)pg * 64;
    const float* ibase = inp + chunkoff + (long)pg * 64;
    uint16_t* obase = xbf_out + chunkoff + (long)pg * 64;

    // single-position softmax+accumulate (MODE 0 path + scalar fallback)
    auto attend = [&](const uint32_t px0, const uint32_t px1, const uint32_t px2,
                      const uint32_t px3, const float* xf) {
        float lg[8];
#if USE_DOT2
#pragma unroll
        for (int kk = 0; kk < 8; ++kk) {
            float a = 0.f;
            a = __builtin_amdgcn_fdot2_f32_bf16(asbf2(qrp[kk][0]), asbf2(px0), a, false);
            a = __builtin_amdgcn_fdot2_f32_bf16(asbf2(qrp[kk][1]), asbf2(px1), a, false);
            a = __builtin_amdgcn_fdot2_f32_bf16(asbf2(qrp[kk][2]), asbf2(px2), a, false);
            a = __builtin_amdgcn_fdot2_f32_bf16(asbf2(qrp[kk][3]), asbf2(px3), a, false);
            lg[kk] = a;
        }
#else
#pragma unroll
        for (int kk = 0; kk < 8; ++kk) {
            float a = 0.f;
#pragma unroll
            for (int i = 0; i < 8; ++i) a += qr[kk][i] * xf[i];
            lg[kk] = a;
        }
#endif
#pragma unroll
        for (int kk = 0; kk < 8; ++kk) lg[kk] = dppadd<0xB1>(lg[kk]);
#pragma unroll
        for (int kk = 0; kk < 8; ++kk) lg[kk] = dppadd<0x4E>(lg[kk]);
#pragma unroll
        for (int kk = 0; kk < 8; ++kk) lg[kk] = dppadd<0x141>(lg[kk]);
        float e[8];
#pragma unroll
        for (int kk = 0; kk < 8; ++kk) e[kk] = exp2f(lg[kk]);
        const float es = ((e[0] + e[1]) + (e[2] + e[3])) + ((e[4] + e[5]) + (e[6] + e[7]));
        const float rinv = __builtin_amdgcn_rcpf(es);
#if USE_PKFMA
        f32x2 xf2[4];
#pragma unroll
        for (int i = 0; i < 4; ++i) xf2[i] = (f32x2){xf[2 * i], xf[2 * i + 1]};
#pragma unroll
        for (int kk = 0; kk < 8; ++kk) {
            const float a = e[kk] * rinv;
            asum[kk] += a;
            const f32x2 a2 = {a, a};
#pragma unroll
            for (int i = 0; i < 4; ++i)
                upd2[kk][i] = __builtin_elementwise_fma(a2, xf2[i], upd2[kk][i]);
        }
#else
#pragma unroll
        for (int kk = 0; kk < 8; ++kk) {
            const float a = e[kk] * rinv;
            asum[kk] += a;
#pragma unroll
            for (int i = 0; i < 8; ++i) upd[kk][i] += a * xf[i];
        }
#endif
    };

    // ---- ILP-2 paired body (MODE 1): two independent positions ----
    auto body1pair = [&](const uint4 a4, const uint4 b4) {
        float xfA[8], xfB[8];
        xfA[0] = bflo(a4.x); xfA[1] = bfhi(a4.x);
        xfA[2] = bflo(a4.y); xfA[3] = bfhi(a4.y);
        xfA[4] = bflo(a4.z); xfA[5] = bfhi(a4.z);
        xfA[6] = bflo(a4.w); xfA[7] = bfhi(a4.w);
        xfB[0] = bflo(b4.x); xfB[1] = bfhi(b4.x);
        xfB[2] = bflo(b4.y); xfB[3] = bfhi(b4.y);
        xfB[4] = bflo(b4.z); xfB[5] = bfhi(b4.z);
        xfB[6] = bflo(b4.w); xfB[7] = bfhi(b4.w);
        float lgA[8], lgB[8];
#if USE_DOT2
#pragma unroll
        for (int kk = 0; kk < 8; ++kk) {
            float a = 0.f, bb = 0.f;
            a = __builtin_amdgcn_fdot2_f32_bf16(asbf2(qrp[kk][0]), asbf2(a4.x), a, false);
            bb = __builtin_amdgcn_fdot2_f32_bf16(asbf2(qrp[kk][0]), asbf2(b4.x), bb, false);
            a = __builtin_amdgcn_fdot2_f32_bf16(asbf2(qrp[kk][1]), asbf2(a4.y), a, false);
            bb = __builtin_amdgcn_fdot2_f32_bf16(asbf2(qrp[kk][1]), asbf2(b4.y), bb, false);
            a = __builtin_amdgcn_fdot2_f32_bf16(asbf2(qrp[kk][2]), asbf2(a4.z), a, false);
            bb = __builtin_amdgcn_fdot2_f32_bf16(asbf2(qrp[kk][2]), asbf2(b4.z), bb, false);
            a = __builtin_amdgcn_fdot2_f32_bf16(asbf2(qrp[kk][3]), asbf2(a4.w), a, false);
            bb = __builtin_amdgcn_fdot2_f32_bf16(asbf2(qrp[kk][3]), asbf2(b4.w), bb, false);
            lgA[kk] = a; lgB[kk] = bb;
        }
#else
#pragma unroll
        for (int kk = 0; kk < 8; ++kk) {
            float a = 0.f, bb = 0.f;
#pragma unroll
            for (int i = 0; i < 8; ++i) { a += qr[kk][i] * xfA[i]; bb += qr[kk][i] * xfB[i]; }
            lgA[kk] = a; lgB[kk] = bb;
        }
#endif
#pragma unroll
        for (int kk = 0; kk < 8; ++kk) { lgA[kk] = dppadd<0xB1>(lgA[kk]); lgB[kk] = dppadd<0xB1>(lgB[kk]); }
#pragma unroll
        for (int kk = 0; kk < 8; ++kk) { lgA[kk] = dppadd<0x4E>(lgA[kk]); lgB[kk] = dppadd<0x4E>(lgB[kk]); }
#pragma unroll
        for (int kk = 0; kk < 8; ++kk) { lgA[kk] = dppadd<0x141>(lgA[kk]); lgB[kk] = dppadd<0x141>(lgB[kk]); }
        float eA[8], eB[8];
#pragma unroll
        for (int kk = 0; kk < 8; ++kk) { eA[kk] = exp2f(lgA[kk]); eB[kk] = exp2f(lgB[kk]); }
        const float esA = ((eA[0] + eA[1]) + (eA[2] + eA[3])) + ((eA[4] + eA[5]) + (eA[6] + eA[7]));
        const float esB = ((eB[0] + eB[1]) + (eB[2] + eB[3])) + ((eB[4] + eB[5]) + (eB[6] + eB[7]));
        const float rinvA = __builtin_amdgcn_rcpf(esA);
        const float rinvB = __builtin_amdgcn_rcpf(esB);
#if USE_PKFMA
        f32x2 xf2A[4], xf2B[4];
#pragma unroll
        for (int i = 0; i < 4; ++i) {
            xf2A[i] = (f32x2){xfA[2 * i], xfA[2 * i + 1]};
            xf2B[i] = (f32x2){xfB[2 * i], xfB[2 * i + 1]};
        }
#pragma unroll
        for (int kk = 0; kk < 8; ++kk) {
            const float aA = eA[kk] * rinvA;
            const float aB = eB[kk] * rinvB;
            asum[kk] += aA + aB;
            const f32x2 aA2 = {aA, aA};
            const f32x2 aB2 = {aB, aB};
#pragma unroll
            for (int i = 0; i < 4; ++i) {
                upd2[kk][i] = __builtin_elementwise_fma(aA2, xf2A[i], upd2[kk][i]);
                upd2[kk][i] = __builtin_elementwise_fma(aB2, xf2B[i], upd2[kk][i]);
            }
        }
#else
#pragma unroll
        for (int kk = 0; kk < 8; ++kk) {
            const float aA = eA[kk] * rinvA;
            const float aB = eB[kk] * rinvB;
            asum[kk] += aA + aB;
#pragma unroll
            for (int i = 0; i < 8; ++i) upd[kk][i] += aA * xfA[i] + aB * xfB[i];
        }
#endif
    };

    auto body0 = [&](const float4 fa, const float4 fb, const int pos) {
        float x8[8] = {fa.x, fa.y, fa.z, fa.w, fb.x, fb.y, fb.z, fb.w};
        float s1 = 0.f, s2 = 0.f;
#pragma unroll
        for (int i = 0; i < 8; ++i) { s1 += x8[i]; s2 += x8[i] * x8[i]; }
        s1 = dppadd<0xB1>(s1); s2 = dppadd<0xB1>(s2);
        s1 = dppadd<0x4E>(s1); s2 = dppadd<0x4E>(s2);
        s1 = dppadd<0x141>(s1); s2 = dppadd<0x141>(s2);
        const float mean = s1 * (1.0f / 64.0f);
        const float var = s2 * (1.0f / 64.0f) - mean * mean;
        const float rstd = rsqrtf(var + LN_EPSf);
        float xf[8];
        u16x8 o;
#pragma unroll
        for (int i = 0; i < 8; ++i) {
            xf[i] = (x8[i] - mean) * rstd * gv[i] + bt[i];
            o[i] = f2bf(xf[i]);
        }
        *(u16x8*)(obase + (long)pos * 2048) = o;  // 2048 = 32*64
        const uint32_t p0 = (uint32_t)o[0] | ((uint32_t)o[1] << 16);
        const uint32_t p1 = (uint32_t)o[2] | ((uint32_t)o[3] << 16);
        const uint32_t p2 = (uint32_t)o[4] | ((uint32_t)o[5] << 16);
        const uint32_t p3 = (uint32_t)o[6] | ((uint32_t)o[7] << 16);
        attend(p0, p1, p2, p3, xf);
    };

    if (MODE == 1) {
        // 8 paired steps; 2-pair ping-pong prefetch (4 uint4 in flight).
        uint4 xA0 = *(const uint4*)(xbase);
        uint4 xB0 = *(const uint4*)(xbase + 2048);
        uint4 xA1 = *(const uint4*)(xbase + 4096);
        uint4 xB1 = *(const uint4*)(xbase + 4096 + 2048);
        int it = 0;
        for (; it < (NITn / 2) - 2; it += 2) {
            uint4 nA0 = *(const uint4*)(xbase + (long)(it + 2) * 4096);
            uint4 nB0 = *(const uint4*)(xbase + (long)(it + 2) * 4096 + 2048);
            body1pair(xA0, xB0); xA0 = nA0; xB0 = nB0;
            uint4 nA1 = *(const uint4*)(xbase + (long)(it + 3) * 4096);
            uint4 nB1 = *(const uint4*)(xbase + (long)(it + 3) * 4096 + 2048);
            body1pair(xA1, xB1); xA1 = nA1; xB1 = nB1;
        }
        body1pair(xA0, xB0);
        body1pair(xA1, xB1);
    } else {
        float4 faA = *(const float4*)(ibase);
        float4 fbA = *(const float4*)(ibase + 4);
        float4 faB = *(const float4*)(ibase + 2048);
        float4 fbB = *(const float4*)(ibase + 2048 + 4);
        int it = 0;
        for (; it < NITn - 2; it += 2) {
            float4 nA0 = *(const float4*)(ibase + (long)(it + 2) * 2048);
            float4 nA1 = *(const float4*)(ibase + (long)(it + 2) * 2048 + 4);
            body0(faA, fbA, it); faA = nA0; fbA = nA1;
            float4 nB0 = *(const float4*)(ibase + (long)(it + 3) * 2048);
            float4 nB1 = *(const float4*)(ibase + (long)(it + 3) * 2048 + 4);
            body0(faB, fbB, it + 1); faB = nB0; fbB = nB1;
        }
        body0(faA, fbA, NITn - 2);
        body0(faB, fbB, NITn - 1);
    }

    // ---- unpack accumulators to the validated tail layout ----
    float upda[8][8];
#if USE_PKFMA
#pragma unroll
    for (int kk = 0; kk < 8; ++kk)
#pragma unroll
        for (int i = 0; i < 4; ++i) {
            upda[kk][2 * i] = upd2[kk][i].x;
            upda[kk][2 * i + 1] = upd2[kk][i].y;
        }
#else
#pragma unroll
    for (int kk = 0; kk < 8; ++kk)
#pragma unroll
        for (int i = 0; i < 8; ++i) upda[kk][i] = upd[kk][i];
#endif

    // ---- tail: DPP ror8 pair-reduce, 16 copies -> LDS (R5/R8-validated) ----
#pragma unroll
    for (int kk = 0; kk < 8; ++kk) {
#pragma unroll
        for (int i = 0; i < 8; ++i) upda[kk][i] = dppadd<0x128>(upda[kk][i]);
        asum[kk] = dppadd<0x128>(asum[kk]);
    }
    const int l = t & 63;
    const int wv = t >> 6;
    if ((l & 8) == 0) {
        const int copy = wv * 4 + (l >> 4);
        float* rb = red + copy * 552 + (l & 7) * 8;
#pragma unroll
        for (int kk = 0; kk < 8; ++kk) {
            float4 u0, u1;
            u0.x = upda[kk][0]; u0.y = upda[kk][1]; u0.z = upda[kk][2]; u0.w = upda[kk][3];
            u1.x = upda[kk][4]; u1.y = upda[kk][5]; u1.z = upda[kk][6]; u1.w = upda[kk][7];
            *(float4*)(rb + kk * 68) = u0;
            *(float4*)(rb + kk * 68 + 4) = u1;
        }
        if ((l & 15) == 0) {
            float4 a0, a1;
            a0.x = asum[0]; a0.y = asum[1]; a0.z = asum[2]; a0.w = asum[3];
            a1.x = asum[4]; a1.y = asum[5]; a1.z = asum[6]; a1.w = asum[7];
            *(float4*)&redas[copy][0] = a0;
            *(float4*)&redas[copy][4] = a1;
        }
    }
    __syncthreads();
    float* pout = partials + (long)(b * PBn + part) * 520;
    if (t < 128) {
        const int kk = t >> 4, dq = t & 15;
        float4 acc = {0.f, 0.f, 0.f, 0.f};
#pragma unroll
        for (int c = 0; c < 16; ++c) {
            float4 v = *(const float4*)(red + c * 552 + kk * 68 + dq * 4);
            acc.x += v.x; acc.y += v.y; acc.z += v.z; acc.w += v.w;
        }
        *(float4*)(pout + kk * 64 + dq * 4) = acc;
    }
    if (t < 8) {
        float a = 0.f;
#pragma unroll
        for (int c = 0; c < 16; ++c) a += redas[c][t];
        pout[512 + t] = a;
    }
}

// ---------------- k3: per-(batch,slot) update + next-iter qk row (R8) ----
__global__ __launch_bounds__(256) void k3_update(
    const float* __restrict__ partials, const float* __restrict__ slots_in,
    const float* __restrict__ Wv,
    const float* __restrict__ wih, const float* __restrict__ whh,
    const float* __restrict__ bih, const float* __restrict__ bhh,
    const float* __restrict__ mg, const float* __restrict__ mb,
    const float* __restrict__ w1, const float* __restrict__ b1,
    const float* __restrict__ w2, const float* __restrict__ b2,
    const float* __restrict__ M, const float* __restrict__ lsg,
    const float* __restrict__ lsb,
    float* __restrict__ slots_out, float* __restrict__ qkout) {
    __shared__ float axn[64];
    __shared__ float updf[64];
    __shared__ float sp[64];
    __shared__ float gi[192];
    __shared__ float gh[192];
    __shared__ float sn[64];
    __shared__ float hln[64];
    __shared__ float hid[256];
    __shared__ float outv[64];
    __shared__ float lnq[64];

    const int t = threadIdx.x;
    const int b = blockIdx.x >> 3;
    const int s = blockIdx.x & 7;
    const float* pp = partials + (long)b * PBn * 520;

    float asum = EPSf;
#pragma unroll
    for (int j = 0; j < PBn; ++j) asum += pp[j * 520 + 512 + s];
    const float rasum = 1.0f / asum;

    if (t < 64) {
        float a = 0.f;
#pragma unroll
        for (int j = 0; j < PBn; ++j) a += pp[j * 520 + s * 64 + t];
        axn[t] = a * rasum;
    } else if (t < 80) {
        const int i = t - 64;
        *(float4*)&sp[i * 4] = *(const float4*)(slots_in + b * 512 + s * 64 + i * 4);
    }
    __syncthreads();

    {
        const int d = t >> 2, h = t & 3;
        const float* wr = Wv + d * 64 + h * 16;
        float acc = 0.f;
#pragma unroll
        for (int u = 0; u < 4; ++u) {
            float4 w4 = *(const float4*)(wr + u * 4);
            float4 a4 = *(const float4*)&axn[h * 16 + u * 4];
            acc += w4.x * a4.x + w4.y * a4.y + w4.z * a4.z + w4.w * a4.w;
        }
        acc = dppadd<0xB1>(acc);
        acc = dppadd<0x4E>(acc);
        if (h == 0) updf[d] = acc;
    }
    __syncthreads();

    for (int w = t; w < 768; w += 256) {
        const int j = w >> 2, h = w & 3;
        const float* wr = wih + j * 64 + h * 16;
        float acc = 0.f;
#pragma unroll
        for (int u = 0; u < 4; ++u) {
            float4 w4 = *(const float4*)(wr + u * 4);
            float4 a4 = *(const float4*)&updf[h * 16 + u * 4];
            acc += w4.x * a4.x + w4.y * a4.y + w4.z * a4.z + w4.w * a4.w;
        }
        acc = dppadd<0xB1>(acc);
        acc = dppadd<0x4E>(acc);
        if (h == 0) gi[j] = acc + bih[j];
    }
    for (int w = t; w < 768; w += 256) {
        const int j = w >> 2, h = w & 3;
        const float* wr = whh + j * 64 + h * 16;
        float acc = 0.f;
#pragma unroll
        for (int u = 0; u < 4; ++u) {
            float4 w4 = *(const float4*)(wr + u * 4);
            float4 a4 = *(const float4*)&sp[h * 16 + u * 4];
            acc += w4.x * a4.x + w4.y * a4.y + w4.z * a4.z + w4.w * a4.w;
        }
        acc = dppadd<0xB1>(acc);
        acc = dppadd<0x4E>(acc);
        if (h == 0) gh[j] = acc + bhh[j];
    }
    __syncthreads();

    if (t < 64) {
        const float ir = gi[t], iz = gi[64 + t], in_ = gi[128 + t];
        const float hr = gh[t], hz = gh[64 + t], hn = gh[128 + t];
        const float r = 1.0f / (1.0f + __expf(-(ir + hr)));
        const float z = 1.0f / (1.0f + __expf(-(iz + hz)));
        const float n = tanhf(in_ + r * hn);
        sn[t] = (1.0f - z) * n + z * sp[t];
    }
    __syncthreads();

    if (t < 16) {
        float4 v4 = *(const float4*)&sn[t * 4];
        float s1 = v4.x + v4.y + v4.z + v4.w;
        float s2 = v4.x * v4.x + v4.y * v4.y + v4.z * v4.z + v4.w * v4.w;
        s1 = dppadd<0xB1>(s1); s2 = dppadd<0xB1>(s2);
        s1 = dppadd<0x4E>(s1); s2 = dppadd<0x4E>(s2);
        s1 = dppadd<0x141>(s1); s2 = dppadd<0x141>(s2);
        s1 = dppadd<0x128>(s1); s2 = dppadd<0x128>(s2);
        const float mean = s1 * (1.0f / 64.0f);
        const float var = s2 * (1.0f / 64.0f) - mean * mean;
        const float rstd = rsqrtf(var + LN_EPSf);
        const float xs[4] = {v4.x, v4.y, v4.z, v4.w};
#pragma unroll
        for (int i = 0; i < 4; ++i) {
            const int dcol = t * 4 + i;
            hln[dcol] = (xs[i] - mean) * rstd * mg[dcol] + mb[dcol];
        }
    }
    __syncthreads();

    for (int w = t; w < 1024; w += 256) {
        const int j = w >> 2, h = w & 3;
        const float* wr = w1 + j * 64 + h * 16;
        float acc = 0.f;
#pragma unroll
        for (int u = 0; u < 4; ++u) {
            float4 w4 = *(const float4*)(wr + u * 4);
            float4 a4 = *(const float4*)&hln[h * 16 + u * 4];
            acc += w4.x * a4.x + w4.y * a4.y + w4.z * a4.z + w4.w * a4.w;
        }
        acc = dppadd<0xB1>(acc);
        acc = dppadd<0x4E>(acc);
        if (h == 0) hid[j] = fmaxf(acc + b1[j], 0.0f);
    }
    __syncthreads();

    {
        const int d = t >> 2, h = t & 3;
        const float* wr = w2 + d * 256 + h * 64;
        float acc = 0.f;
#pragma unroll
        for (int u = 0; u < 16; ++u) {
            float4 w4 = *(const float4*)(wr + u * 4);
            float4 h4 = *(const float4*)&hid[h * 64 + u * 4];
            acc += w4.x * h4.x + w4.y * h4.y + w4.z * h4.z + w4.w * h4.w;
        }
        acc = dppadd<0xB1>(acc);
        acc = dppadd<0x4E>(acc);
        if (h == 0) {
            const float val = sn[d] + acc + b2[d];
            slots_out[(long)b * 512 + s * 64 + d] = val;
            outv[d] = val;
        }
    }
    __syncthreads();

    if (t < 16) {
        float4 v4 = *(const float4*)&outv[t * 4];
        float s1 = v4.x + v4.y + v4.z + v4.w;
        float s2 = v4.x * v4.x + v4.y * v4.y + v4.z * v4.z + v4.w * v4.w;
        s1 = dppadd<0xB1>(s1); s2 = dppadd<0xB1>(s2);
        s1 = dppadd<0x4E>(s1); s2 = dppadd<0x4E>(s2);
        s1 = dppadd<0x141>(s1); s2 = dppadd<0x141>(s2);
        s1 = dppadd<0x128>(s1); s2 = dppadd<0x128>(s2);
        const float mean = s1 * (1.0f / 64.0f);
        const float var = s2 * (1.0f / 64.0f) - mean * mean;
        const float rstd = rsqrtf(var + LN_EPSf);
        const float xs[4] = {v4.x, v4.y, v4.z, v4.w};
#pragma unroll
        for (int i = 0; i < 4; ++i) {
            const int dcol = t * 4 + i;
            lnq[dcol] = (xs[i] - mean) * rstd * lsg[dcol] + lsb[dcol];
        }
    }
    __syncthreads();
    if (t < 64) {
        float a = 0.f;
#pragma unroll 8
        for (int e = 0; e < 64; ++e) a += lnq[e] * M[e * 64 + t];
        qkout[b * 512 + s * 64 + t] = a;
    }
}

extern "C" void kernel_launch(void* const* d_in, const int* in_sizes, int n_in,
                              void* d_out, int out_size, void* d_ws, size_t ws_size,
                              hipStream_t stream) {
    const float* inputs = (const float*)d_in[0];
    const float* noise = (const float*)d_in[1];
    const float* mu = (const float*)d_in[2];
    const float* ls = (const float*)d_in[3];
    const float* Wq = (const float*)d_in[4];
    const float* Wk = (const float*)d_in[5];
    const float* Wv = (const float*)d_in[6];
    const float* wih = (const float*)d_in[7];
    const float* whh = (const float*)d_in[8];
    const float* bih = (const float*)d_in[9];
    const float* bhh = (const float*)d_in[10];
    const float* lng = (const float*)d_in[11];
    const float* lnb = (const float*)d_in[12];
    const float* lsg = (const float*)d_in[13];
    const float* lsb = (const float*)d_in[14];
    const float* mg = (const float*)d_in[15];
    const float* mb = (const float*)d_in[16];
    const float* w1 = (const float*)d_in[17];
    const float* b1 = (const float*)d_in[18];
    const float* w2 = (const float*)d_in[19];
    const float* b2 = (const float*)d_in[20];

    char* ws = (char*)d_ws;
    float* slots = (float*)ws;                                   // 256 KiB
    float* Mm = (float*)(ws + 262144);                           // 16 KiB
    float* qk = (float*)(ws + 262144 + 16384);                   // 256 KiB
    uint16_t* xbf = (uint16_t*)(ws + 262144 + 16384 + 262144);   // 64 MiB
    float* parts = (float*)(ws + 262144 + 16384 + 262144 + (1 << 26));  // ~2.2 MiB

    kM<<<16, 256, 0, stream>>>(Wq, Wk, Mm);
    kinit_qk_full<<<Bn, 256, 0, stream>>>(noise, mu, ls, Mm, lsg, lsb, slots, qk);
    for (int it = 0; it < 3; ++it) {
        if (it == 0)
            k2_attn<0><<<Bn * PBn, 256, 0, stream>>>(inputs, xbf, xbf, qk, lng, lnb, parts);
        else
            k2_attn<1><<<Bn * PBn, 256, 0, stream>>>(inputs, xbf, xbf, qk, lng, lnb, parts);
        float* dst = (it == 2) ? (float*)d_out : slots;
        k3_update<<<Bn * Kn, 256, 0, stream>>>(parts, slots, Wv, wih, whh, bih, bhh,
                                               mg, mb, w1, b1, w2, b2, Mm, lsg, lsb,
                                               dst, qk);
    }
}

// Round 17
// 171.408 us; speedup vs baseline: 1.0260x; 1.0260x over previous
//
#include <hip/hip_runtime.h>
#include <cstdint>

#define Bn 128
#define Nn 4096
#define Dn 64
#define Kn 8
#define PBn 8
#define NCHUNKn (Nn / PBn)   // 512
#define NITn (NCHUNKn / 32)  // 16
#define LN_EPSf 1e-5f
#define EPSf 1e-8f
#define LOG2Ef 1.4426950408889634f

typedef unsigned short u16x8 __attribute__((ext_vector_type(8)));
typedef float f32x2 __attribute__((ext_vector_type(2)));

#if __has_builtin(__builtin_amdgcn_fdot2_f32_bf16)
#define USE_DOT2 1
typedef __bf16 bf16v2 __attribute__((ext_vector_type(2)));
static __device__ __forceinline__ bf16v2 asbf2(uint32_t u) {
    union { uint32_t u; bf16v2 v; } c; c.u = u; return c.v;
}
#else
#define USE_DOT2 0
#endif

#if __has_builtin(__builtin_elementwise_fma)
#define USE_PKFMA 1
#else
#define USE_PKFMA 0
#endif

static __device__ __forceinline__ uint16_t f2bf(float f) {
    union { float f; uint32_t u; } v; v.f = f;
    return (uint16_t)((v.u + 0x7fffu + ((v.u >> 16) & 1u)) >> 16);
}
static __device__ __forceinline__ float bflo(uint32_t u) {
    union { uint32_t u; float f; } v; v.u = u << 16; return v.f;
}
static __device__ __forceinline__ float bfhi(uint32_t u) {
    union { uint32_t u; float f; } v; v.u = u & 0xffff0000u; return v.f;
}

// DPP butterfly add (validated R3-R16): 0xB1 ^1, 0x4E ^2, 0x141 ^7, 0x128 ror8.
template <int CTRL>
static __device__ __forceinline__ float dppadd(float x) {
    int p = __builtin_amdgcn_update_dpp(0, __float_as_int(x), CTRL, 0xf, 0xf, false);
    return x + __int_as_float(p);
}

// ---------------- kM: M = (Wq^T @ Wk) / sqrt(D) * log2(e) ----------------
__global__ __launch_bounds__(256) void kM(const float* __restrict__ Wq,
                                          const float* __restrict__ Wk,
                                          float* __restrict__ M) {
    const int idx = blockIdx.x * 256 + threadIdx.x;  // 4096
    const int e = idx >> 6, f = idx & 63;
    float acc = 0.f;
#pragma unroll 8
    for (int d = 0; d < 64; ++d) acc += Wq[d * 64 + e] * Wk[d * 64 + f];
    M[idx] = acc * 0.125f * LOG2Ef;
}

// ------- kinit_qk: slots = mu+exp(ls)*noise; qk0 = LN(slots)@M (R8) ------
__global__ __launch_bounds__(256) void kinit_qk_full(
    const float* __restrict__ noise, const float* __restrict__ mu,
    const float* __restrict__ ls, const float* __restrict__ M,
    const float* __restrict__ lsg, const float* __restrict__ lsb,
    float* __restrict__ slots, float* __restrict__ qk) {
    __shared__ float sraw[Kn * Dn];
    __shared__ float sln[Kn][68];
    const int t = threadIdx.x;
    const int b = blockIdx.x;

    if (t < 128) {
        const int base = (b * 128 + t) * 4;
        const int d = base & 63;
        float4 nz = *(const float4*)(noise + base);
        float4 m4 = *(const float4*)(mu + d);
        float4 s4 = *(const float4*)(ls + d);
        float4 o;
        o.x = m4.x + __expf(s4.x) * nz.x;
        o.y = m4.y + __expf(s4.y) * nz.y;
        o.z = m4.z + __expf(s4.z) * nz.z;
        o.w = m4.w + __expf(s4.w) * nz.w;
        *(float4*)(slots + base) = o;
        *(float4*)(sraw + t * 4) = o;
    }
    __syncthreads();
    if (t < 128) {
        const int row = t >> 4, l16 = t & 15;
        float4 v4 = *(const float4*)(sraw + row * 64 + l16 * 4);
        float s1 = v4.x + v4.y + v4.z + v4.w;
        float s2 = v4.x * v4.x + v4.y * v4.y + v4.z * v4.z + v4.w * v4.w;
        s1 = dppadd<0xB1>(s1); s2 = dppadd<0xB1>(s2);
        s1 = dppadd<0x4E>(s1); s2 = dppadd<0x4E>(s2);
        s1 = dppadd<0x141>(s1); s2 = dppadd<0x141>(s2);
        s1 = dppadd<0x128>(s1); s2 = dppadd<0x128>(s2);
        const float mean = s1 * (1.0f / 64.0f);
        const float var = s2 * (1.0f / 64.0f) - mean * mean;
        const float rstd = rsqrtf(var + LN_EPSf);
        const float xs[4] = {v4.x, v4.y, v4.z, v4.w};
#pragma unroll
        for (int i = 0; i < 4; ++i) {
            const int dcol = l16 * 4 + i;
            sln[row][dcol] = (xs[i] - mean) * rstd * lsg[dcol] + lsb[dcol];
        }
    }
    __syncthreads();
    for (int o = t; o < 512; o += 256) {
        const int kk = o >> 6, j = o & 63;
        float a = 0.f;
#pragma unroll 8
        for (int e = 0; e < 64; ++e) a += sln[kk][e] * M[e * 64 + j];
        qk[b * 512 + o] = a;
    }
}

// ---------------- k2: attention pass over an N-chunk (R14 core) ----------
// MODE 0: read raw fp32 inputs, inline LN (dc-lane DPP), write xbf, attend.
// MODE 1: read bf16 xbf.  2-deep named-register prefetch.
// Logits via v_dot2_f32_bf16; upd accumulate via v_pk_fma_f32; es tree-sum;
// no min-waves bound (R11's (256,3) caused a 74 MB spill).
template <int MODE>
__global__ __launch_bounds__(256) void k2_attn(
    const float* __restrict__ inp, const uint16_t* __restrict__ xbf_in,
    uint16_t* __restrict__ xbf_out, const float* __restrict__ qkg,
    const float* __restrict__ lng, const float* __restrict__ lnb,
    float* __restrict__ partials) {
    __shared__ float qld[Kn][64];
    __shared__ float red[16 * 552];
    __shared__ float redas[16][8];

    const int t = threadIdx.x;
    const int b = blockIdx.x >> 3;
    const int part = blockIdx.x & 7;

    if (t < 128) *(float4*)(&qld[0][0] + t * 4) = *(const float4*)(qkg + b * 512 + t * 4);
    __syncthreads();

    const int dc = t & 7;
    const int pg = t >> 3;  // 0..31

#if USE_DOT2
    uint32_t qrp[8][4];
#pragma unroll
    for (int kk = 0; kk < 8; ++kk)
#pragma unroll
        for (int p = 0; p < 4; ++p)
            qrp[kk][p] = (uint32_t)f2bf(qld[kk][dc * 8 + 2 * p]) |
                         ((uint32_t)f2bf(qld[kk][dc * 8 + 2 * p + 1]) << 16);
#else
    float qr[8][8];
#pragma unroll
    for (int kk = 0; kk < 8; ++kk) {
        float4 q0 = *(const float4*)&qld[kk][dc * 8];
        float4 q1 = *(const float4*)&qld[kk][dc * 8 + 4];
        qr[kk][0] = q0.x; qr[kk][1] = q0.y; qr[kk][2] = q0.z; qr[kk][3] = q0.w;
        qr[kk][4] = q1.x; qr[kk][5] = q1.y; qr[kk][6] = q1.z; qr[kk][7] = q1.w;
    }
#endif

    // LN gamma/beta for my 8 dims (MODE 0 only)
    float gv[8], bt[8];
    if (MODE == 0) {
#pragma unroll
        for (int i = 0; i < 8; ++i) { gv[i] = lng[dc * 8 + i]; bt[i] = lnb[dc * 8 + i]; }
    }

#if USE_PKFMA
    f32x2 upd2[8][4];
#pragma unroll
    for (int kk = 0; kk < 8; ++kk)
#pragma unroll
        for (int i = 0; i < 4; ++i) upd2[kk][i] = (f32x2){0.f, 0.f};
#else
    float upd[8][8];
#pragma unroll
    for (int kk = 0; kk < 8; ++kk)
#pragma unroll
        for (int i = 0; i < 8; ++i) upd[kk][i] = 0.f;
#endif
    float asum[8];
#pragma unroll
    for (int kk = 0; kk < 8; ++kk) asum[kk] = 0.f;

    const long chunkoff = ((long)b * Nn + part * NCHUNKn) * 64 + dc * 8;
    const uint16_t* xbase = xbf_in + chunkoff + (long)pg * 64;
    const float* ibase = inp + chunkoff + (long)pg * 64;
    uint16_t* obase = xbf_out + chunkoff + (long)pg * 64;

    // shared inner softmax+accumulate given packed bf16 x (px) and fp32 xf
    auto attend = [&](const uint32_t px0, const uint32_t px1, const uint32_t px2,
                      const uint32_t px3, const float* xf) {
        float lg[8];
#if USE_DOT2
#pragma unroll
        for (int kk = 0; kk < 8; ++kk) {
            float a = 0.f;
            a = __builtin_amdgcn_fdot2_f32_bf16(asbf2(qrp[kk][0]), asbf2(px0), a, false);
            a = __builtin_amdgcn_fdot2_f32_bf16(asbf2(qrp[kk][1]), asbf2(px1), a, false);
            a = __builtin_amdgcn_fdot2_f32_bf16(asbf2(qrp[kk][2]), asbf2(px2), a, false);
            a = __builtin_amdgcn_fdot2_f32_bf16(asbf2(qrp[kk][3]), asbf2(px3), a, false);
            lg[kk] = a;
        }
#else
#pragma unroll
        for (int kk = 0; kk < 8; ++kk) {
            float a = 0.f;
#pragma unroll
            for (int i = 0; i < 8; ++i) a += qr[kk][i] * xf[i];
            lg[kk] = a;
        }
#endif
#pragma unroll
        for (int kk = 0; kk < 8; ++kk) lg[kk] = dppadd<0xB1>(lg[kk]);
#pragma unroll
        for (int kk = 0; kk < 8; ++kk) lg[kk] = dppadd<0x4E>(lg[kk]);
#pragma unroll
        for (int kk = 0; kk < 8; ++kk) lg[kk] = dppadd<0x141>(lg[kk]);
        float e[8];
#pragma unroll
        for (int kk = 0; kk < 8; ++kk) e[kk] = exp2f(lg[kk]);
        const float es = ((e[0] + e[1]) + (e[2] + e[3])) + ((e[4] + e[5]) + (e[6] + e[7]));
        const float rinv = __builtin_amdgcn_rcpf(es);
#if USE_PKFMA
        f32x2 xf2[4];
#pragma unroll
        for (int i = 0; i < 4; ++i) xf2[i] = (f32x2){xf[2 * i], xf[2 * i + 1]};
#pragma unroll
        for (int kk = 0; kk < 8; ++kk) {
            const float a = e[kk] * rinv;
            asum[kk] += a;
            const f32x2 a2 = {a, a};
#pragma unroll
            for (int i = 0; i < 4; ++i)
                upd2[kk][i] = __builtin_elementwise_fma(a2, xf2[i], upd2[kk][i]);
        }
#else
#pragma unroll
        for (int kk = 0; kk < 8; ++kk) {
            const float a = e[kk] * rinv;
            asum[kk] += a;
#pragma unroll
            for (int i = 0; i < 8; ++i) upd[kk][i] += a * xf[i];
        }
#endif
    };

    auto body1 = [&](const uint4 x4) {
        float xf[8];
        xf[0] = bflo(x4.x); xf[1] = bfhi(x4.x);
        xf[2] = bflo(x4.y); xf[3] = bfhi(x4.y);
        xf[4] = bflo(x4.z); xf[5] = bfhi(x4.z);
        xf[6] = bflo(x4.w); xf[7] = bfhi(x4.w);
        attend(x4.x, x4.y, x4.z, x4.w, xf);
    };

    auto body0 = [&](const float4 fa, const float4 fb, const int pos) {
        float x8[8] = {fa.x, fa.y, fa.z, fa.w, fb.x, fb.y, fb.z, fb.w};
        float s1 = 0.f, s2 = 0.f;
#pragma unroll
        for (int i = 0; i < 8; ++i) { s1 += x8[i]; s2 += x8[i] * x8[i]; }
        s1 = dppadd<0xB1>(s1); s2 = dppadd<0xB1>(s2);
        s1 = dppadd<0x4E>(s1); s2 = dppadd<0x4E>(s2);
        s1 = dppadd<0x141>(s1); s2 = dppadd<0x141>(s2);
        const float mean = s1 * (1.0f / 64.0f);
        const float var = s2 * (1.0f / 64.0f) - mean * mean;
        const float rstd = rsqrtf(var + LN_EPSf);
        float xf[8];
        u16x8 o;
#pragma unroll
        for (int i = 0; i < 8; ++i) {
            xf[i] = (x8[i] - mean) * rstd * gv[i] + bt[i];
            o[i] = f2bf(xf[i]);
        }
        *(u16x8*)(obase + (long)pos * 2048) = o;  // 2048 = 32*64
        const uint32_t p0 = (uint32_t)o[0] | ((uint32_t)o[1] << 16);
        const uint32_t p1 = (uint32_t)o[2] | ((uint32_t)o[3] << 16);
        const uint32_t p2 = (uint32_t)o[4] | ((uint32_t)o[5] << 16);
        const uint32_t p3 = (uint32_t)o[6] | ((uint32_t)o[7] << 16);
        attend(p0, p1, p2, p3, xf);
    };

    if (MODE == 1) {
        uint4 xrA = *(const uint4*)(xbase);
        uint4 xrB = *(const uint4*)(xbase + 2048);
        int it = 0;
        for (; it < NITn - 2; it += 2) {
            uint4 nA = *(const uint4*)(xbase + (long)(it + 2) * 2048);
            body1(xrA); xrA = nA;
            uint4 nB = *(const uint4*)(xbase + (long)(it + 3) * 2048);
            body1(xrB); xrB = nB;
        }
        body1(xrA);
        body1(xrB);
    } else {
        float4 faA = *(const float4*)(ibase);
        float4 fbA = *(const float4*)(ibase + 4);
        float4 faB = *(const float4*)(ibase + 2048);
        float4 fbB = *(const float4*)(ibase + 2048 + 4);
        int it = 0;
        for (; it < NITn - 2; it += 2) {
            float4 nA0 = *(const float4*)(ibase + (long)(it + 2) * 2048);
            float4 nA1 = *(const float4*)(ibase + (long)(it + 2) * 2048 + 4);
            body0(faA, fbA, it); faA = nA0; fbA = nA1;
            float4 nB0 = *(const float4*)(ibase + (long)(it + 3) * 2048);
            float4 nB1 = *(const float4*)(ibase + (long)(it + 3) * 2048 + 4);
            body0(faB, fbB, it + 1); faB = nB0; fbB = nB1;
        }
        body0(faA, fbA, NITn - 2);
        body0(faB, fbB, NITn - 1);
    }

    // ---- unpack accumulators to the validated tail layout ----
    float upda[8][8];
#if USE_PKFMA
#pragma unroll
    for (int kk = 0; kk < 8; ++kk)
#pragma unroll
        for (int i = 0; i < 4; ++i) {
            upda[kk][2 * i] = upd2[kk][i].x;
            upda[kk][2 * i + 1] = upd2[kk][i].y;
        }
#else
#pragma unroll
    for (int kk = 0; kk < 8; ++kk)
#pragma unroll
        for (int i = 0; i < 8; ++i) upda[kk][i] = upd[kk][i];
#endif

    // ---- tail: DPP ror8 pair-reduce, 16 copies -> LDS (R5/R8-validated) ----
#pragma unroll
    for (int kk = 0; kk < 8; ++kk) {
#pragma unroll
        for (int i = 0; i < 8; ++i) upda[kk][i] = dppadd<0x128>(upda[kk][i]);
        asum[kk] = dppadd<0x128>(asum[kk]);
    }
    const int l = t & 63;
    const int wv = t >> 6;
    if ((l & 8) == 0) {
        const int copy = wv * 4 + (l >> 4);
        float* rb = red + copy * 552 + (l & 7) * 8;
#pragma unroll
        for (int kk = 0; kk < 8; ++kk) {
            float4 u0, u1;
            u0.x = upda[kk][0]; u0.y = upda[kk][1]; u0.z = upda[kk][2]; u0.w = upda[kk][3];
            u1.x = upda[kk][4]; u1.y = upda[kk][5]; u1.z = upda[kk][6]; u1.w = upda[kk][7];
            *(float4*)(rb + kk * 68) = u0;
            *(float4*)(rb + kk * 68 + 4) = u1;
        }
        if ((l & 15) == 0) {
            float4 a0, a1;
            a0.x = asum[0]; a0.y = asum[1]; a0.z = asum[2]; a0.w = asum[3];
            a1.x = asum[4]; a1.y = asum[5]; a1.z = asum[6]; a1.w = asum[7];
            *(float4*)&redas[copy][0] = a0;
            *(float4*)&redas[copy][4] = a1;
        }
    }
    __syncthreads();
    float* pout = partials + (long)(b * PBn + part) * 520;
    if (t < 128) {
        const int kk = t >> 4, dq = t & 15;
        float4 acc = {0.f, 0.f, 0.f, 0.f};
#pragma unroll
        for (int c = 0; c < 16; ++c) {
            float4 v = *(const float4*)(red + c * 552 + kk * 68 + dq * 4);
            acc.x += v.x; acc.y += v.y; acc.z += v.z; acc.w += v.w;
        }
        *(float4*)(pout + kk * 64 + dq * 4) = acc;
    }
    if (t < 8) {
        float a = 0.f;
#pragma unroll
        for (int c = 0; c < 16; ++c) a += redas[c][t];
        pout[512 + t] = a;
    }
}

// ---------------- k3: per-(batch,slot) update + next-iter qk row (R8) ----
__global__ __launch_bounds__(256) void k3_update(
    const float* __restrict__ partials, const float* __restrict__ slots_in,
    const float* __restrict__ Wv,
    const float* __restrict__ wih, const float* __restrict__ whh,
    const float* __restrict__ bih, const float* __restrict__ bhh,
    const float* __restrict__ mg, const float* __restrict__ mb,
    const float* __restrict__ w1, const float* __restrict__ b1,
    const float* __restrict__ w2, const float* __restrict__ b2,
    const float* __restrict__ M, const float* __restrict__ lsg,
    const float* __restrict__ lsb,
    float* __restrict__ slots_out, float* __restrict__ qkout) {
    __shared__ float axn[64];
    __shared__ float updf[64];
    __shared__ float sp[64];
    __shared__ float gi[192];
    __shared__ float gh[192];
    __shared__ float sn[64];
    __shared__ float hln[64];
    __shared__ float hid[256];
    __shared__ float outv[64];
    __shared__ float lnq[64];

    const int t = threadIdx.x;
    const int b = blockIdx.x >> 3;
    const int s = blockIdx.x & 7;
    const float* pp = partials + (long)b * PBn * 520;

    float asum = EPSf;
#pragma unroll
    for (int j = 0; j < PBn; ++j) asum += pp[j * 520 + 512 + s];
    const float rasum = 1.0f / asum;

    if (t < 64) {
        float a = 0.f;
#pragma unroll
        for (int j = 0; j < PBn; ++j) a += pp[j * 520 + s * 64 + t];
        axn[t] = a * rasum;
    } else if (t < 80) {
        const int i = t - 64;
        *(float4*)&sp[i * 4] = *(const float4*)(slots_in + b * 512 + s * 64 + i * 4);
    }
    __syncthreads();

    {
        const int d = t >> 2, h = t & 3;
        const float* wr = Wv + d * 64 + h * 16;
        float acc = 0.f;
#pragma unroll
        for (int u = 0; u < 4; ++u) {
            float4 w4 = *(const float4*)(wr + u * 4);
            float4 a4 = *(const float4*)&axn[h * 16 + u * 4];
            acc += w4.x * a4.x + w4.y * a4.y + w4.z * a4.z + w4.w * a4.w;
        }
        acc = dppadd<0xB1>(acc);
        acc = dppadd<0x4E>(acc);
        if (h == 0) updf[d] = acc;
    }
    __syncthreads();

    for (int w = t; w < 768; w += 256) {
        const int j = w >> 2, h = w & 3;
        const float* wr = wih + j * 64 + h * 16;
        float acc = 0.f;
#pragma unroll
        for (int u = 0; u < 4; ++u) {
            float4 w4 = *(const float4*)(wr + u * 4);
            float4 a4 = *(const float4*)&updf[h * 16 + u * 4];
            acc += w4.x * a4.x + w4.y * a4.y + w4.z * a4.z + w4.w * a4.w;
        }
        acc = dppadd<0xB1>(acc);
        acc = dppadd<0x4E>(acc);
        if (h == 0) gi[j] = acc + bih[j];
    }
    for (int w = t; w < 768; w += 256) {
        const int j = w >> 2, h = w & 3;
        const float* wr = whh + j * 64 + h * 16;
        float acc = 0.f;
#pragma unroll
        for (int u = 0; u < 4; ++u) {
            float4 w4 = *(const float4*)(wr + u * 4);
            float4 a4 = *(const float4*)&sp[h * 16 + u * 4];
            acc += w4.x * a4.x + w4.y * a4.y + w4.z * a4.z + w4.w * a4.w;
        }
        acc = dppadd<0xB1>(acc);
        acc = dppadd<0x4E>(acc);
        if (h == 0) gh[j] = acc + bhh[j];
    }
    __syncthreads();

    if (t < 64) {
        const float ir = gi[t], iz = gi[64 + t], in_ = gi[128 + t];
        const float hr = gh[t], hz = gh[64 + t], hn = gh[128 + t];
        const float r = 1.0f / (1.0f + __expf(-(ir + hr)));
        const float z = 1.0f / (1.0f + __expf(-(iz + hz)));
        const float n = tanhf(in_ + r * hn);
        sn[t] = (1.0f - z) * n + z * sp[t];
    }
    __syncthreads();

    if (t < 16) {
        float4 v4 = *(const float4*)&sn[t * 4];
        float s1 = v4.x + v4.y + v4.z + v4.w;
        float s2 = v4.x * v4.x + v4.y * v4.y + v4.z * v4.z + v4.w * v4.w;
        s1 = dppadd<0xB1>(s1); s2 = dppadd<0xB1>(s2);
        s1 = dppadd<0x4E>(s1); s2 = dppadd<0x4E>(s2);
        s1 = dppadd<0x141>(s1); s2 = dppadd<0x141>(s2);
        s1 = dppadd<0x128>(s1); s2 = dppadd<0x128>(s2);
        const float mean = s1 * (1.0f / 64.0f);
        const float var = s2 * (1.0f / 64.0f) - mean * mean;
        const float rstd = rsqrtf(var + LN_EPSf);
        const float xs[4] = {v4.x, v4.y, v4.z, v4.w};
#pragma unroll
        for (int i = 0; i < 4; ++i) {
            const int dcol = t * 4 + i;
            hln[dcol] = (xs[i] - mean) * rstd * mg[dcol] + mb[dcol];
        }
    }
    __syncthreads();

    for (int w = t; w < 1024; w += 256) {
        const int j = w >> 2, h = w & 3;
        const float* wr = w1 + j * 64 + h * 16;
        float acc = 0.f;
#pragma unroll
        for (int u = 0; u < 4; ++u) {
            float4 w4 = *(const float4*)(wr + u * 4);
            float4 a4 = *(const float4*)&hln[h * 16 + u * 4];
            acc += w4.x * a4.x + w4.y * a4.y + w4.z * a4.z + w4.w * a4.w;
        }
        acc = dppadd<0xB1>(acc);
        acc = dppadd<0x4E>(acc);
        if (h == 0) hid[j] = fmaxf(acc + b1[j], 0.0f);
    }
    __syncthreads();

    {
        const int d = t >> 2, h = t & 3;
        const float* wr = w2 + d * 256 + h * 64;
        float acc = 0.f;
#pragma unroll
        for (int u = 0; u < 16; ++u) {
            float4 w4 = *(const float4*)(wr + u * 4);
            float4 h4 = *(const float4*)&hid[h * 64 + u * 4];
            acc += w4.x * h4.x + w4.y * h4.y + w4.z * h4.z + w4.w * h4.w;
        }
        acc = dppadd<0xB1>(acc);
        acc = dppadd<0x4E>(acc);
        if (h == 0) {
            const float val = sn[d] + acc + b2[d];
            slots_out[(long)b * 512 + s * 64 + d] = val;
            outv[d] = val;
        }
    }
    __syncthreads();

    if (t < 16) {
        float4 v4 = *(const float4*)&outv[t * 4];
        float s1 = v4.x + v4.y + v4.z + v4.w;
        float s2 = v4.x * v4.x + v4.y * v4.y + v4.z * v4.z + v4.w * v4.w;
        s1 = dppadd<0xB1>(s1); s2 = dppadd<0xB1>(s2);
        s1 = dppadd<0x4E>(s1); s2 = dppadd<0x4E>(s2);
        s1 = dppadd<0x141>(s1); s2 = dppadd<0x141>(s2);
        s1 = dppadd<0x128>(s1); s2 = dppadd<0x128>(s2);
        const float mean = s1 * (1.0f / 64.0f);
        const float var = s2 * (1.0f / 64.0f) - mean * mean;
        const float rstd = rsqrtf(var + LN_EPSf);
        const float xs[4] = {v4.x, v4.y, v4.z, v4.w};
#pragma unroll
        for (int i = 0; i < 4; ++i) {
            const int dcol = t * 4 + i;
            lnq[dcol] = (xs[i] - mean) * rstd * lsg[dcol] + lsb[dcol];
        }
    }
    __syncthreads();
    if (t < 64) {
        float a = 0.f;
#pragma unroll 8
        for (int e = 0; e < 64; ++e) a += lnq[e] * M[e * 64 + t];
        qkout[b * 512 + s * 64 + t] = a;
    }
}

extern "C" void kernel_launch(void* const* d_in, const int* in_sizes, int n_in,
                              void* d_out, int out_size, void* d_ws, size_t ws_size,
                              hipStream_t stream) {
    const float* inputs = (const float*)d_in[0];
    const float* noise = (const float*)d_in[1];
    const float* mu = (const float*)d_in[2];
    const float* ls = (const float*)d_in[3];
    const float* Wq = (const float*)d_in[4];
    const float* Wk = (const float*)d_in[5];
    const float* Wv = (const float*)d_in[6];
    const float* wih = (const float*)d_in[7];
    const float* whh = (const float*)d_in[8];
    const float* bih = (const float*)d_in[9];
    const float* bhh = (const float*)d_in[10];
    const float* lng = (const float*)d_in[11];
    const float* lnb = (const float*)d_in[12];
    const float* lsg = (const float*)d_in[13];
    const float* lsb = (const float*)d_in[14];
    const float* mg = (const float*)d_in[15];
    const float* mb = (const float*)d_in[16];
    const float* w1 = (const float*)d_in[17];
    const float* b1 = (const float*)d_in[18];
    const float* w2 = (const float*)d_in[19];
    const float* b2 = (const float*)d_in[20];

    char* ws = (char*)d_ws;
    float* slots = (float*)ws;                                   // 256 KiB
    float* Mm = (float*)(ws + 262144);                           // 16 KiB
    float* qk = (float*)(ws + 262144 + 16384);                   // 256 KiB
    uint16_t* xbf = (uint16_t*)(ws + 262144 + 16384 + 262144);   // 64 MiB
    float* parts = (float*)(ws + 262144 + 16384 + 262144 + (1 << 26));  // ~2.2 MiB

    kM<<<16, 256, 0, stream>>>(Wq, Wk, Mm);
    kinit_qk_full<<<Bn, 256, 0, stream>>>(noise, mu, ls, Mm, lsg, lsb, slots, qk);
    for (int it = 0; it < 3; ++it) {
        if (it == 0)
            k2_attn<0><<<Bn * PBn, 256, 0, stream>>>(inputs, xbf, xbf, qk, lng, lnb, parts);
        else
            k2_attn<1><<<Bn * PBn, 256, 0, stream>>>(inputs, xbf, xbf, qk, lng, lnb, parts);
        float* dst = (it == 2) ? (float*)d_out : slots;
        k3_update<<<Bn * Kn, 256, 0, stream>>>(parts, slots, Wv, wih, whh, bih, bhh,
                                               mg, mb, w1, b1, w2, b2, Mm, lsg, lsb,
                                               dst, qk);
    }
}